// Round 5
// baseline (1505.945 us; speedup 1.0000x reference)
//
#include <hip/hip_runtime.h>

#define NN 100000
#define NE 1600000
#define NG 1024
#define D 64
#define DE 6
#define FAN 70
#define EPS 1e-5f

#define ENC_NEGINF 0x007FFFFFu
#define NINF (-__builtin_inff())

#define NBUK 196      // dst buckets of 512 nodes
#define TILE 1600     // edges per binA block -> 1000 blocks
#define ACAP 20       // LDS stage capacity per bucket per binA block (lambda=8.2)
#define GCAP 10240    // global per-bucket capacity (mean 8163)
#define BCAP 10240    // binB LDS esrc capacity

__device__ __forceinline__ unsigned enc(float f) {
    unsigned u = __float_as_uint(f);
    return (u & 0x80000000u) ? ~u : (u | 0x80000000u);
}
__device__ __forceinline__ float dec(unsigned u) {
    return (u & 0x80000000u) ? __uint_as_float(u & 0x7FFFFFFFu) : __uint_as_float(~u);
}
__device__ __forceinline__ unsigned bfr(float f) {   // fp32 -> bf16 bits, RNE
    unsigned u = __float_as_uint(f);
    return (u + 0x7FFFu + ((u >> 16) & 1)) >> 16;
}
__device__ __forceinline__ float blo(unsigned w) { return __uint_as_float(w << 16); }
__device__ __forceinline__ float bhi(unsigned w) { return __uint_as_float(w & 0xFFFF0000u); }

__global__ void k_fill_u32x4(uint4* __restrict__ p, unsigned v, int n4) {
    int i = blockIdx.x * 256 + threadIdx.x;
    if (i < n4) p[i] = make_uint4(v, v, v, v);
}

// fp32 [NN][64] -> bf16-packed [NN][32] u32
__global__ void k_cast(const float4* __restrict__ in, uint2* __restrict__ out, int n4) {
    int i = blockIdx.x * 256 + threadIdx.x;
    if (i < n4) {
        float4 v = in[i];
        out[i] = make_uint2(bfr(v.x) | (bfr(v.y) << 16), bfr(v.z) | (bfr(v.w) << 16));
    }
}

// ---------------- scans for rowptr ----------------
#define SCAN_BS 512
__global__ void k_scan1(const int* __restrict__ counts, int* __restrict__ excl,
                        int* __restrict__ bsum) {
    __shared__ int s[SCAN_BS];
    int t = threadIdx.x;
    int i = blockIdx.x * SCAN_BS + t;
    int c = (i < NN) ? counts[i] : 0;
    s[t] = c;
    __syncthreads();
    for (int off = 1; off < SCAN_BS; off <<= 1) {
        int v = (t >= off) ? s[t - off] : 0;
        __syncthreads();
        s[t] += v;
        __syncthreads();
    }
    if (i < NN) excl[i] = s[t] - c;
    if (t == SCAN_BS - 1) bsum[blockIdx.x] = s[t];
}

__global__ void k_scan2(int* __restrict__ bsum, int nb) {
    __shared__ int s[256];
    int t = threadIdx.x;
    int c = (t < nb) ? bsum[t] : 0;
    s[t] = c;
    __syncthreads();
    for (int off = 1; off < 256; off <<= 1) {
        int v = (t >= off) ? s[t - off] : 0;
        __syncthreads();
        s[t] += v;
        __syncthreads();
    }
    if (t < nb) bsum[t] = s[t] - c;
}

__global__ void k_scan3(int* __restrict__ rowptr, const int* __restrict__ bsum) {
    int i = blockIdx.x * 256 + threadIdx.x;
    if (i < NN) rowptr[i] += bsum[i >> 9];
    if (i == NN) rowptr[NN] = NE;
}

// pass A: bin edges by dst>>9; small tiles + small LDS stage -> latency hidden by TLP
__launch_bounds__(256)
__global__ void k_binA(const int* __restrict__ src, const int* __restrict__ dst,
                       int* __restrict__ gcnt, unsigned* __restrict__ gbuck) {
    __shared__ unsigned stage[NBUK][ACAP];   // 15.7 KB
    __shared__ int cnt[NBUK];
    int tid = threadIdx.x;
    for (int i = tid; i < NBUK; i += 256) cnt[i] = 0;
    __syncthreads();
    int e0 = blockIdx.x * TILE;
    int e1 = min(e0 + TILE, NE);
    for (int e = e0 + tid; e < e1; e += 256) {
        int d = dst[e];
        int s = src[e];
        int b = d >> 9;
        unsigned ent = ((unsigned)s << 9) | (unsigned)(d & 511);
        int pos = atomicAdd(&cnt[b], 1);
        if (pos < ACAP) stage[b][pos] = ent;
        else {  // rare spill (P~1e-4): direct append
            int gp = atomicAdd(&gcnt[b], 1);
            gbuck[(size_t)b * GCAP + gp] = ent;
        }
    }
    __syncthreads();
    int wv = tid >> 6, ln = tid & 63;
    for (int b = wv; b < NBUK; b += 4) {
        int c = min(cnt[b], ACAP);
        if (c == 0) continue;
        int base = 0;
        if (ln == 0) base = atomicAdd(&gcnt[b], c);
        base = __shfl(base, 0, 64);
        if (ln < c) gbuck[(size_t)b * GCAP + base + ln] = stage[b][ln];
    }
}

// pass B: one block per bucket; LDS scatter then coalesced stream-out
__launch_bounds__(512)
__global__ void k_binB(const unsigned* __restrict__ gbuck, const int* __restrict__ gcnt,
                       const int* __restrict__ rowptr, int* __restrict__ esrc) {
    __shared__ int curs[512];
    __shared__ unsigned el[BCAP];            // 40 KB
    int k = blockIdx.x;
    int tid = threadIdx.x;
    int nb = k << 9;
    int nend = min(nb + 512, NN);
    int rowbase = rowptr[nb];
    int regsz = rowptr[nend] - rowbase;
    curs[tid] = (nb + tid < nend) ? rowptr[nb + tid] - rowbase : 0;
    __syncthreads();
    int total = gcnt[k];
    if (regsz <= BCAP) {
        for (int i = tid; i < total; i += 512) {
            unsigned ent = gbuck[(size_t)k * GCAP + i];
            int pos = atomicAdd(&curs[ent & 511], 1);
            el[pos] = ent >> 9;
        }
        __syncthreads();
        for (int i = tid; i < regsz; i += 512) esrc[rowbase + i] = (int)el[i];
    } else {  // capacity fallback: direct global scatter (correct, slower)
        for (int i = tid; i < total; i += 512) {
            unsigned ent = gbuck[(size_t)k * GCAP + i];
            int pos = atomicAdd(&curs[ent & 511], 1);
            esrc[rowbase + pos] = (int)(ent >> 9);
        }
    }
}

// ---------------- edge_attr seg-max + dst histogram (fused; layer-invariant) ----------------
__global__ void k_scatter_e(const float* __restrict__ ea, const int* __restrict__ dst,
                            unsigned* __restrict__ eaggk, int* __restrict__ counts) {
    int e = blockIdx.x * 32 + (threadIdx.x >> 3);
    if (e >= NE) return;
    int t = threadIdx.x & 7;
    int d = __ldg(&dst[e]);
    if (t == 7) { atomicAdd(&counts[d], 1); return; }
    if (t >= DE) return;
    unsigned k = enc(ea[e * DE + t]);
    unsigned* addr = &eaggk[d * DE + t];
    if (k > *addr) atomicMax(addr, k);
}

// ---------------- gather-max: half-wave per node, raw bf16 maxima out ----------------
__global__ void k_agg(const unsigned* __restrict__ Xb, const int* __restrict__ rowptr,
                      const int* __restrict__ esrc, unsigned* __restrict__ Ab) {
    int n = blockIdx.x * 8 + (threadIdx.x >> 5);
    int lt = threadIdx.x & 31;
    if (n >= NN) return;
    int rs = rowptr[n], re = rowptr[n + 1];
    float m0 = NINF, m1 = NINF, p0 = NINF, p1 = NINF;
    int j = rs;
    for (; j + 8 <= re; j += 8) {
        int s0 = esrc[j], s1 = esrc[j + 1], s2 = esrc[j + 2], s3 = esrc[j + 3];
        int s4 = esrc[j + 4], s5 = esrc[j + 5], s6 = esrc[j + 6], s7 = esrc[j + 7];
        unsigned v0 = Xb[(size_t)s0 * 32 + lt], v1 = Xb[(size_t)s1 * 32 + lt];
        unsigned v2 = Xb[(size_t)s2 * 32 + lt], v3 = Xb[(size_t)s3 * 32 + lt];
        unsigned v4 = Xb[(size_t)s4 * 32 + lt], v5 = Xb[(size_t)s5 * 32 + lt];
        unsigned v6 = Xb[(size_t)s6 * 32 + lt], v7 = Xb[(size_t)s7 * 32 + lt];
        m0 = fmaxf(m0, fmaxf(fmaxf(blo(v0), blo(v1)), fmaxf(blo(v2), blo(v3))));
        p0 = fmaxf(p0, fmaxf(fmaxf(blo(v4), blo(v5)), fmaxf(blo(v6), blo(v7))));
        m1 = fmaxf(m1, fmaxf(fmaxf(bhi(v0), bhi(v1)), fmaxf(bhi(v2), bhi(v3))));
        p1 = fmaxf(p1, fmaxf(fmaxf(bhi(v4), bhi(v5)), fmaxf(bhi(v6), bhi(v7))));
    }
    for (; j + 2 <= re; j += 2) {
        unsigned v0 = Xb[(size_t)esrc[j] * 32 + lt], v1 = Xb[(size_t)esrc[j + 1] * 32 + lt];
        m0 = fmaxf(m0, blo(v0)); p0 = fmaxf(p0, blo(v1));
        m1 = fmaxf(m1, bhi(v0)); p1 = fmaxf(p1, bhi(v1));
    }
    if (j < re) {
        unsigned v = Xb[(size_t)esrc[j] * 32 + lt];
        m0 = fmaxf(m0, blo(v)); m1 = fmaxf(m1, bhi(v));
    }
    m0 = fmaxf(m0, p0);
    m1 = fmaxf(m1, p1);
    Ab[(size_t)n * 32 + lt] = bfr(m0) | (bfr(m1) << 16);
}

// ---------------- GEMM: decode A (+prev-layer norm/relu), compute h, stats ----------------
__launch_bounds__(256)
__global__ void k_gemm(const unsigned* __restrict__ Ab, const unsigned* __restrict__ eaggk,
                       const float* __restrict__ ss, int apply,
                       const float* __restrict__ W, const float* __restrict__ b,
                       unsigned* __restrict__ Hb, float* __restrict__ stats) {
    __shared__ float Wl[FAN][D];    // 17.9 KB
    __shared__ float Ag[64][74];    // 18.9 KB
    __shared__ float ls[128];

    int tid = threadIdx.x;
    int n0 = blockIdx.x * 64;

    for (int i = tid; i < FAN * D; i += 256) Wl[i >> 6][i & 63] = W[i];
    for (int i = tid; i < 64 * 32; i += 256) {
        int r = i >> 5, c2 = i & 31;
        int n = n0 + r;
        unsigned wv = (n < NN) ? Ab[(size_t)n * 32 + c2] : 0xFF80FF80u;
        float a0 = blo(wv), a1 = bhi(wv);
        if (apply) {
            a0 = (a0 == NINF) ? 0.f : fmaxf(fmaf(a0, ss[2 * c2], ss[D + 2 * c2]), 0.f);
            a1 = (a1 == NINF) ? 0.f : fmaxf(fmaf(a1, ss[2 * c2 + 1], ss[D + 2 * c2 + 1]), 0.f);
        } else {
            a0 = (a0 == NINF) ? 0.f : a0;
            a1 = (a1 == NINF) ? 0.f : a1;
        }
        *(float2*)&Ag[r][2 * c2] = make_float2(a0, a1);
    }
    for (int i = tid; i < 64 * 8; i += 256) {
        int r = i >> 3, c = i & 7;
        int n = n0 + r;
        float v = 0.f;
        if (c < DE && n < NN) {
            unsigned u = eaggk[n * DE + c];
            v = (u == ENC_NEGINF) ? 0.f : dec(u);
        }
        Ag[r][64 + c] = v;
    }
    if (tid < 128) ls[tid] = 0.f;
    __syncthreads();

    int tr = tid >> 4, tc = tid & 15;
    int r0 = tr * 4, c0 = tc * 4;
    float acc[4][4];
    #pragma unroll
    for (int i = 0; i < 4; i++)
        #pragma unroll
        for (int jj = 0; jj < 4; jj++) acc[i][jj] = 0.f;

    for (int k = 0; k < FAN; k++) {
        float4 wv = *(const float4*)&Wl[k][c0];
        float a0 = Ag[r0 + 0][k];
        float a1 = Ag[r0 + 1][k];
        float a2 = Ag[r0 + 2][k];
        float a3 = Ag[r0 + 3][k];
        acc[0][0] = fmaf(a0, wv.x, acc[0][0]); acc[0][1] = fmaf(a0, wv.y, acc[0][1]);
        acc[0][2] = fmaf(a0, wv.z, acc[0][2]); acc[0][3] = fmaf(a0, wv.w, acc[0][3]);
        acc[1][0] = fmaf(a1, wv.x, acc[1][0]); acc[1][1] = fmaf(a1, wv.y, acc[1][1]);
        acc[1][2] = fmaf(a1, wv.z, acc[1][2]); acc[1][3] = fmaf(a1, wv.w, acc[1][3]);
        acc[2][0] = fmaf(a2, wv.x, acc[2][0]); acc[2][1] = fmaf(a2, wv.y, acc[2][1]);
        acc[2][2] = fmaf(a2, wv.z, acc[2][2]); acc[2][3] = fmaf(a2, wv.w, acc[2][3]);
        acc[3][0] = fmaf(a3, wv.x, acc[3][0]); acc[3][1] = fmaf(a3, wv.y, acc[3][1]);
        acc[3][2] = fmaf(a3, wv.z, acc[3][2]); acc[3][3] = fmaf(a3, wv.w, acc[3][3]);
    }

    float4 bb = *(const float4*)&b[c0];
    float cs[4] = {0.f, 0.f, 0.f, 0.f};
    float cq[4] = {0.f, 0.f, 0.f, 0.f};
    #pragma unroll
    for (int i = 0; i < 4; i++) {
        int n = n0 + r0 + i;
        if (n < NN) {
            float ox = acc[i][0] + bb.x, oy = acc[i][1] + bb.y;
            float oz = acc[i][2] + bb.z, ow = acc[i][3] + bb.w;
            uint2 pk = make_uint2(bfr(ox) | (bfr(oy) << 16), bfr(oz) | (bfr(ow) << 16));
            *(uint2*)&Hb[(size_t)n * 32 + (c0 >> 1)] = pk;
            cs[0] += ox; cs[1] += oy; cs[2] += oz; cs[3] += ow;
            cq[0] += ox * ox; cq[1] += oy * oy; cq[2] += oz * oz; cq[3] += ow * ow;
        }
    }
    #pragma unroll
    for (int jj = 0; jj < 4; jj++) {
        atomicAdd(&ls[c0 + jj], cs[jj]);
        atomicAdd(&ls[64 + c0 + jj], cq[jj]);
    }
    __syncthreads();
    if (tid < 128) atomicAdd(&stats[tid], ls[tid]);
}

__global__ void k_finalize_stats(const float* __restrict__ stats, const float* __restrict__ g,
                                 const float* __restrict__ beta, float* __restrict__ ss) {
    int j = threadIdx.x;  // 64 threads
    float mean = stats[j] * (1.0f / NN);
    float var = stats[64 + j] * (1.0f / NN) - mean * mean;
    float sc = rsqrtf(var + EPS) * g[j];
    ss[j] = sc;
    ss[64 + j] = beta[j] - mean * sc;
}

// graph offsets from sorted batch
__global__ void k_gptr(const int* __restrict__ batch, int* __restrict__ gptr) {
    int i = blockIdx.x * 256 + threadIdx.x;
    if (i >= NN) return;
    int b = batch[i];
    int prev = (i == 0) ? -1 : batch[i - 1];
    for (int g = prev + 1; g <= b; ++g) gptr[g] = i;
    if (i == NN - 1) {
        for (int g = b + 1; g <= NG; ++g) gptr[g] = NN;
    }
}

// pool(gather) + norm/relu + dot: half-wave per graph
__global__ void k_gfinal(const unsigned* __restrict__ Hb, const int* __restrict__ gptr,
                         const float* __restrict__ ss, const float* __restrict__ lw,
                         const float* __restrict__ lb, float* __restrict__ out) {
    int g = blockIdx.x * 8 + (threadIdx.x >> 5);
    int lt = threadIdx.x & 31;
    if (g >= NG) return;
    int rs = gptr[g], re = gptr[g + 1];
    float m0 = NINF, m1 = NINF, p0 = NINF, p1 = NINF;
    int n = rs;
    for (; n + 4 <= re; n += 4) {
        unsigned v0 = Hb[(size_t)(n + 0) * 32 + lt];
        unsigned v1 = Hb[(size_t)(n + 1) * 32 + lt];
        unsigned v2 = Hb[(size_t)(n + 2) * 32 + lt];
        unsigned v3 = Hb[(size_t)(n + 3) * 32 + lt];
        m0 = fmaxf(m0, fmaxf(blo(v0), blo(v1))); m1 = fmaxf(m1, fmaxf(bhi(v0), bhi(v1)));
        p0 = fmaxf(p0, fmaxf(blo(v2), blo(v3))); p1 = fmaxf(p1, fmaxf(bhi(v2), bhi(v3)));
    }
    for (; n < re; ++n) {
        unsigned v = Hb[(size_t)n * 32 + lt];
        m0 = fmaxf(m0, blo(v)); m1 = fmaxf(m1, bhi(v));
    }
    m0 = fmaxf(m0, p0);
    m1 = fmaxf(m1, p1);
    float a0 = (m0 == NINF) ? 0.f : fmaxf(fmaf(m0, ss[2 * lt], ss[D + 2 * lt]), 0.f);
    float a1 = (m1 == NINF) ? 0.f : fmaxf(fmaf(m1, ss[2 * lt + 1], ss[D + 2 * lt + 1]), 0.f);
    float p = fmaf(a0, lw[2 * lt], a1 * lw[2 * lt + 1]);
    #pragma unroll
    for (int off = 1; off < 32; off <<= 1) p += __shfl_xor(p, off);
    if (lt == 0) out[g] = p + lb[0];
}

extern "C" void kernel_launch(void* const* d_in, const int* in_sizes, int n_in,
                              void* d_out, int out_size, void* d_ws, size_t ws_size,
                              hipStream_t stream) {
    const float* x     = (const float*)d_in[0];
    const int*   ei    = (const int*)d_in[1];
    const float* ea    = (const float*)d_in[2];
    const int*   batch = (const int*)d_in[3];
    const float* Wp[3] = {(const float*)d_in[4],  (const float*)d_in[8],  (const float*)d_in[12]};
    const float* bp[3] = {(const float*)d_in[5],  (const float*)d_in[9],  (const float*)d_in[13]};
    const float* gp[3] = {(const float*)d_in[6],  (const float*)d_in[10], (const float*)d_in[14]};
    const float* tp[3] = {(const float*)d_in[7],  (const float*)d_in[11], (const float*)d_in[15]};
    const float* lw    = (const float*)d_in[16];
    const float* lb    = (const float*)d_in[17];
    float* out = (float*)d_out;

    const int* src = ei;
    const int* dst = ei + NE;

    // workspace layout (u32 words; fill targets 16B-aligned)
    unsigned* w = (unsigned*)d_ws;
    int*      rowptr = (int*)w;                    // 100004
    int*      counts = (int*)(w + 100004);         // 100004
    int*      esrc   = (int*)(w + 200008);         // 1600000
    unsigned* eaggk  = w + 1800008;                // 600000
    int*      bsum   = (int*)(w + 2400008);        // 256
    float*    stats  = (float*)(w + 2400264);      // 128
    float*    ss     = (float*)(w + 2400392);      // 128
    int*      gptr   = (int*)(w + 2400520);        // 1028
    int*      gcnt   = (int*)(w + 2401548);        // 212
    unsigned* gbuck  = w + 2401760;                // 196*10240 = 2007040
    unsigned* Xb0    = w + 4408800;                // 3200000
    unsigned* Hb1    = w + 7608800;                // 3200000
    unsigned* Hb2    = w + 10808800;               // 3200000  (end: 56.0 MB)

    const int NB = (NN + SCAN_BS - 1) / SCAN_BS;   // 196

    // --- zero fills ---
    k_fill_u32x4<<<(25001 + 255) / 256, 256, 0, stream>>>((uint4*)counts, 0u, 25001);
    k_fill_u32x4<<<1, 53, 0, stream>>>((uint4*)gcnt, 0u, 53);
    k_fill_u32x4<<<(150000 + 255) / 256, 256, 0, stream>>>((uint4*)eaggk, ENC_NEGINF, 150000);

    // --- edge_attr seg-max + dst histogram (fused) ---
    k_scatter_e<<<NE / 32, 256, 0, stream>>>(ea, dst, eaggk, counts);

    // --- CSR build: write-coalesced 2-pass binning ---
    k_binA<<<(NE + TILE - 1) / TILE, 256, 0, stream>>>(src, dst, gcnt, gbuck);
    k_scan1<<<NB, SCAN_BS, 0, stream>>>(counts, rowptr, bsum);
    k_scan2<<<1, 256, 0, stream>>>(bsum, NB);
    k_scan3<<<(NN + 1 + 255) / 256, 256, 0, stream>>>(rowptr, bsum);
    k_binB<<<NBUK, 512, 0, stream>>>(gbuck, gcnt, rowptr, esrc);

    // --- bf16 cast + graph offsets ---
    k_cast<<<(NN * 16 + 255) / 256, 256, 0, stream>>>((const float4*)x, (uint2*)Xb0, NN * 16);
    k_gptr<<<(NN + 255) / 256, 256, 0, stream>>>(batch, gptr);

    // --- 3 layers: agg (raw bf16 maxima) -> gemm (decode + fused prev norm/relu) ---
    const unsigned* ain[3] = {Xb0, Hb1, Hb2};
    unsigned* abuf[3] = {Hb2, Xb0, Hb1};
    unsigned* hbuf[3] = {Hb1, Hb2, Xb0};
    for (int l = 0; l < 3; ++l) {
        k_agg<<<NN / 8, 256, 0, stream>>>(ain[l], rowptr, esrc, abuf[l]);
        k_fill_u32x4<<<1, 32, 0, stream>>>((uint4*)stats, 0u, 32);
        k_gemm<<<(NN + 63) / 64, 256, 0, stream>>>(abuf[l], eaggk, ss, l > 0 ? 1 : 0,
                                                   Wp[l], bp[l], hbuf[l], stats);
        k_finalize_stats<<<1, 64, 0, stream>>>(stats, gp[l], tp[l], ss);
    }

    // --- pooled gather + final norm/relu/dot ---
    k_gfinal<<<NG / 8, 256, 0, stream>>>(Xb0, gptr, ss, lw, lb, out);
}

// Round 6
// 546.510 us; speedup vs baseline: 2.7556x; 2.7556x over previous
//
#include <hip/hip_runtime.h>

#define NN 100000
#define NE 1600000
#define NG 1024
#define D 64
#define DE 6
#define FAN 70
#define EPS 1e-5f

#define ENC_NEGINF 0x007FFFFFu
#define NINF (-__builtin_inff())

#define NBUK 196      // dst buckets of 512 nodes
#define TILE 1600     // edges per binA block
#define NBLKA 1000    // NE / TILE
#define ACAP 24       // per-(bucket,block) deterministic slot capacity (lambda=8.16)
#define SCAP 1024     // per-bucket spill capacity (rare path)
#define BCAP 10240    // binB LDS esrc capacity

__device__ __forceinline__ unsigned enc(float f) {
    unsigned u = __float_as_uint(f);
    return (u & 0x80000000u) ? ~u : (u | 0x80000000u);
}
__device__ __forceinline__ float dec(unsigned u) {
    return (u & 0x80000000u) ? __uint_as_float(u & 0x7FFFFFFFu) : __uint_as_float(~u);
}
__device__ __forceinline__ unsigned bfr(float f) {   // fp32 -> bf16 bits, RNE
    unsigned u = __float_as_uint(f);
    return (u + 0x7FFFu + ((u >> 16) & 1)) >> 16;
}
__device__ __forceinline__ float blo(unsigned w) { return __uint_as_float(w << 16); }
__device__ __forceinline__ float bhi(unsigned w) { return __uint_as_float(w & 0xFFFF0000u); }

__global__ void k_fill_u32x4(uint4* __restrict__ p, unsigned v, int n4) {
    int i = blockIdx.x * 256 + threadIdx.x;
    if (i < n4) p[i] = make_uint4(v, v, v, v);
}

// fp32 [NN][64] -> bf16-packed [NN][32] u32
__global__ void k_cast(const float4* __restrict__ in, uint2* __restrict__ out, int n4) {
    int i = blockIdx.x * 256 + threadIdx.x;
    if (i < n4) {
        float4 v = in[i];
        out[i] = make_uint2(bfr(v.x) | (bfr(v.y) << 16), bfr(v.z) | (bfr(v.w) << 16));
    }
}

// ---------------- scans for rowptr ----------------
#define SCAN_BS 512
__global__ void k_scan1(const int* __restrict__ counts, int* __restrict__ excl,
                        int* __restrict__ bsum) {
    __shared__ int s[SCAN_BS];
    int t = threadIdx.x;
    int i = blockIdx.x * SCAN_BS + t;
    int c = (i < NN) ? counts[i] : 0;
    s[t] = c;
    __syncthreads();
    for (int off = 1; off < SCAN_BS; off <<= 1) {
        int v = (t >= off) ? s[t - off] : 0;
        __syncthreads();
        s[t] += v;
        __syncthreads();
    }
    if (i < NN) excl[i] = s[t] - c;
    if (t == SCAN_BS - 1) bsum[blockIdx.x] = s[t];
}

__global__ void k_scan2(int* __restrict__ bsum, int nb) {
    __shared__ int s[256];
    int t = threadIdx.x;
    int c = (t < nb) ? bsum[t] : 0;
    s[t] = c;
    __syncthreads();
    for (int off = 1; off < 256; off <<= 1) {
        int v = (t >= off) ? s[t - off] : 0;
        __syncthreads();
        s[t] += v;
        __syncthreads();
    }
    if (t < nb) bsum[t] = s[t] - c;
}

__global__ void k_scan3(int* __restrict__ rowptr, const int* __restrict__ bsum) {
    int i = blockIdx.x * 256 + threadIdx.x;
    if (i < NN) rowptr[i] += bsum[i >> 9];
    if (i == NN) rowptr[NN] = NE;
}

// pass A: deterministic slots gbuck[b][blk][ACAP] — NO global atomics in hot path
__launch_bounds__(256)
__global__ void k_binA(const int* __restrict__ src, const int* __restrict__ dst,
                       unsigned* __restrict__ gbuck, int* __restrict__ cntA,
                       int* __restrict__ scnt, unsigned* __restrict__ sbuf) {
    __shared__ int cnt[NBUK];
    int tid = threadIdx.x, blk = blockIdx.x;
    for (int i = tid; i < NBUK; i += 256) cnt[i] = 0;
    __syncthreads();
    int e0 = blk * TILE;
    int e1 = min(e0 + TILE, NE);
    for (int e = e0 + tid; e < e1; e += 256) {
        int d = dst[e];
        int s = src[e];
        int b = d >> 9;
        unsigned ent = ((unsigned)s << 9) | (unsigned)(d & 511);
        int pos = atomicAdd(&cnt[b], 1);
        if (pos < ACAP) gbuck[((size_t)b * NBLKA + blk) * ACAP + pos] = ent;
        else {  // ~1e-6 per pair: global spill, negligible contention
            int sp = atomicAdd(&scnt[b], 1);
            if (sp < SCAP) sbuf[b * SCAP + sp] = ent;
        }
    }
    __syncthreads();
    for (int i = tid; i < NBUK; i += 256) cntA[blk * NBUK + i] = min(cnt[i], ACAP);
}

// pass B: one block per bucket; walk 1000 slices, LDS scatter, coalesced stream-out
__launch_bounds__(512)
__global__ void k_binB(const unsigned* __restrict__ gbuck, const int* __restrict__ cntA,
                       const int* __restrict__ scnt, const unsigned* __restrict__ sbuf,
                       const int* __restrict__ rowptr, int* __restrict__ esrc) {
    __shared__ int curs[512];
    __shared__ unsigned el[BCAP];            // 40 KB
    int b = blockIdx.x;
    int tid = threadIdx.x;
    int nb = b << 9;
    int nend = min(nb + 512, NN);
    int rowbase = rowptr[nb];
    int regsz = rowptr[nend] - rowbase;
    curs[tid] = (nb + tid < nend) ? rowptr[nb + tid] - rowbase : 0;
    __syncthreads();
    int sc = min(scnt[b], SCAP);
    if (regsz <= BCAP) {
        for (int blk = tid; blk < NBLKA; blk += 512) {
            int c = cntA[blk * NBUK + b];
            const unsigned* p = &gbuck[((size_t)b * NBLKA + blk) * ACAP];
            for (int i = 0; i < c; ++i) {
                unsigned ent = p[i];
                int pos = atomicAdd(&curs[ent & 511], 1);
                el[pos] = ent >> 9;
            }
        }
        for (int i = tid; i < sc; i += 512) {
            unsigned ent = sbuf[b * SCAP + i];
            int pos = atomicAdd(&curs[ent & 511], 1);
            el[pos] = ent >> 9;
        }
        __syncthreads();
        for (int i = tid; i < regsz; i += 512) esrc[rowbase + i] = (int)el[i];
    } else {  // capacity fallback: direct global scatter (correct, slower)
        for (int blk = tid; blk < NBLKA; blk += 512) {
            int c = cntA[blk * NBUK + b];
            const unsigned* p = &gbuck[((size_t)b * NBLKA + blk) * ACAP];
            for (int i = 0; i < c; ++i) {
                unsigned ent = p[i];
                int pos = atomicAdd(&curs[ent & 511], 1);
                esrc[rowbase + pos] = (int)(ent >> 9);
            }
        }
        for (int i = tid; i < sc; i += 512) {
            unsigned ent = sbuf[b * SCAP + i];
            int pos = atomicAdd(&curs[ent & 511], 1);
            esrc[rowbase + pos] = (int)(ent >> 9);
        }
    }
}

// ---------------- edge_attr seg-max + dst histogram (fused; layer-invariant) ----------------
__global__ void k_scatter_e(const float* __restrict__ ea, const int* __restrict__ dst,
                            unsigned* __restrict__ eaggk, int* __restrict__ counts) {
    int e = blockIdx.x * 32 + (threadIdx.x >> 3);
    if (e >= NE) return;
    int t = threadIdx.x & 7;
    int d = __ldg(&dst[e]);
    if (t == 7) { atomicAdd(&counts[d], 1); return; }
    if (t >= DE) return;
    unsigned k = enc(ea[e * DE + t]);
    unsigned* addr = &eaggk[d * DE + t];
    if (k > *addr) atomicMax(addr, k);
}

// ---------------- gather-max: half-wave per node, raw bf16 maxima out ----------------
__global__ void k_agg(const unsigned* __restrict__ Xb, const int* __restrict__ rowptr,
                      const int* __restrict__ esrc, unsigned* __restrict__ Ab) {
    int n = blockIdx.x * 8 + (threadIdx.x >> 5);
    int lt = threadIdx.x & 31;
    if (n >= NN) return;
    int rs = rowptr[n], re = rowptr[n + 1];
    float m0 = NINF, m1 = NINF, p0 = NINF, p1 = NINF;
    int j = rs;
    for (; j + 8 <= re; j += 8) {
        int s0 = esrc[j], s1 = esrc[j + 1], s2 = esrc[j + 2], s3 = esrc[j + 3];
        int s4 = esrc[j + 4], s5 = esrc[j + 5], s6 = esrc[j + 6], s7 = esrc[j + 7];
        unsigned v0 = Xb[(size_t)s0 * 32 + lt], v1 = Xb[(size_t)s1 * 32 + lt];
        unsigned v2 = Xb[(size_t)s2 * 32 + lt], v3 = Xb[(size_t)s3 * 32 + lt];
        unsigned v4 = Xb[(size_t)s4 * 32 + lt], v5 = Xb[(size_t)s5 * 32 + lt];
        unsigned v6 = Xb[(size_t)s6 * 32 + lt], v7 = Xb[(size_t)s7 * 32 + lt];
        m0 = fmaxf(m0, fmaxf(fmaxf(blo(v0), blo(v1)), fmaxf(blo(v2), blo(v3))));
        p0 = fmaxf(p0, fmaxf(fmaxf(blo(v4), blo(v5)), fmaxf(blo(v6), blo(v7))));
        m1 = fmaxf(m1, fmaxf(fmaxf(bhi(v0), bhi(v1)), fmaxf(bhi(v2), bhi(v3))));
        p1 = fmaxf(p1, fmaxf(fmaxf(bhi(v4), bhi(v5)), fmaxf(bhi(v6), bhi(v7))));
    }
    for (; j + 2 <= re; j += 2) {
        unsigned v0 = Xb[(size_t)esrc[j] * 32 + lt], v1 = Xb[(size_t)esrc[j + 1] * 32 + lt];
        m0 = fmaxf(m0, blo(v0)); p0 = fmaxf(p0, blo(v1));
        m1 = fmaxf(m1, bhi(v0)); p1 = fmaxf(p1, bhi(v1));
    }
    if (j < re) {
        unsigned v = Xb[(size_t)esrc[j] * 32 + lt];
        m0 = fmaxf(m0, blo(v)); m1 = fmaxf(m1, bhi(v));
    }
    m0 = fmaxf(m0, p0);
    m1 = fmaxf(m1, p1);
    Ab[(size_t)n * 32 + lt] = bfr(m0) | (bfr(m1) << 16);
}

// ---------------- GEMM: decode A (+prev-layer norm/relu), compute h, stats ----------------
__launch_bounds__(256)
__global__ void k_gemm(const unsigned* __restrict__ Ab, const unsigned* __restrict__ eaggk,
                       const float* __restrict__ ss, int apply,
                       const float* __restrict__ W, const float* __restrict__ b,
                       unsigned* __restrict__ Hb, float* __restrict__ stats) {
    __shared__ float Wl[FAN][D];    // 17.9 KB
    __shared__ float Ag[64][74];    // 18.9 KB
    __shared__ float ls[128];

    int tid = threadIdx.x;
    int n0 = blockIdx.x * 64;

    for (int i = tid; i < FAN * D; i += 256) Wl[i >> 6][i & 63] = W[i];
    for (int i = tid; i < 64 * 32; i += 256) {
        int r = i >> 5, c2 = i & 31;
        int n = n0 + r;
        unsigned wv = (n < NN) ? Ab[(size_t)n * 32 + c2] : 0xFF80FF80u;
        float a0 = blo(wv), a1 = bhi(wv);
        if (apply) {
            a0 = (a0 == NINF) ? 0.f : fmaxf(fmaf(a0, ss[2 * c2], ss[D + 2 * c2]), 0.f);
            a1 = (a1 == NINF) ? 0.f : fmaxf(fmaf(a1, ss[2 * c2 + 1], ss[D + 2 * c2 + 1]), 0.f);
        } else {
            a0 = (a0 == NINF) ? 0.f : a0;
            a1 = (a1 == NINF) ? 0.f : a1;
        }
        *(float2*)&Ag[r][2 * c2] = make_float2(a0, a1);
    }
    for (int i = tid; i < 64 * 8; i += 256) {
        int r = i >> 3, c = i & 7;
        int n = n0 + r;
        float v = 0.f;
        if (c < DE && n < NN) {
            unsigned u = eaggk[n * DE + c];
            v = (u == ENC_NEGINF) ? 0.f : dec(u);
        }
        Ag[r][64 + c] = v;
    }
    if (tid < 128) ls[tid] = 0.f;
    __syncthreads();

    int tr = tid >> 4, tc = tid & 15;
    int r0 = tr * 4, c0 = tc * 4;
    float acc[4][4];
    #pragma unroll
    for (int i = 0; i < 4; i++)
        #pragma unroll
        for (int jj = 0; jj < 4; jj++) acc[i][jj] = 0.f;

    for (int k = 0; k < FAN; k++) {
        float4 wv = *(const float4*)&Wl[k][c0];
        float a0 = Ag[r0 + 0][k];
        float a1 = Ag[r0 + 1][k];
        float a2 = Ag[r0 + 2][k];
        float a3 = Ag[r0 + 3][k];
        acc[0][0] = fmaf(a0, wv.x, acc[0][0]); acc[0][1] = fmaf(a0, wv.y, acc[0][1]);
        acc[0][2] = fmaf(a0, wv.z, acc[0][2]); acc[0][3] = fmaf(a0, wv.w, acc[0][3]);
        acc[1][0] = fmaf(a1, wv.x, acc[1][0]); acc[1][1] = fmaf(a1, wv.y, acc[1][1]);
        acc[1][2] = fmaf(a1, wv.z, acc[1][2]); acc[1][3] = fmaf(a1, wv.w, acc[1][3]);
        acc[2][0] = fmaf(a2, wv.x, acc[2][0]); acc[2][1] = fmaf(a2, wv.y, acc[2][1]);
        acc[2][2] = fmaf(a2, wv.z, acc[2][2]); acc[2][3] = fmaf(a2, wv.w, acc[2][3]);
        acc[3][0] = fmaf(a3, wv.x, acc[3][0]); acc[3][1] = fmaf(a3, wv.y, acc[3][1]);
        acc[3][2] = fmaf(a3, wv.z, acc[3][2]); acc[3][3] = fmaf(a3, wv.w, acc[3][3]);
    }

    float4 bb = *(const float4*)&b[c0];
    float cs[4] = {0.f, 0.f, 0.f, 0.f};
    float cq[4] = {0.f, 0.f, 0.f, 0.f};
    #pragma unroll
    for (int i = 0; i < 4; i++) {
        int n = n0 + r0 + i;
        if (n < NN) {
            float ox = acc[i][0] + bb.x, oy = acc[i][1] + bb.y;
            float oz = acc[i][2] + bb.z, ow = acc[i][3] + bb.w;
            uint2 pk = make_uint2(bfr(ox) | (bfr(oy) << 16), bfr(oz) | (bfr(ow) << 16));
            *(uint2*)&Hb[(size_t)n * 32 + (c0 >> 1)] = pk;
            cs[0] += ox; cs[1] += oy; cs[2] += oz; cs[3] += ow;
            cq[0] += ox * ox; cq[1] += oy * oy; cq[2] += oz * oz; cq[3] += ow * ow;
        }
    }
    #pragma unroll
    for (int jj = 0; jj < 4; jj++) {
        atomicAdd(&ls[c0 + jj], cs[jj]);
        atomicAdd(&ls[64 + c0 + jj], cq[jj]);
    }
    __syncthreads();
    if (tid < 128) atomicAdd(&stats[tid], ls[tid]);
}

__global__ void k_finalize_stats(const float* __restrict__ stats, const float* __restrict__ g,
                                 const float* __restrict__ beta, float* __restrict__ ss) {
    int j = threadIdx.x;  // 64 threads
    float mean = stats[j] * (1.0f / NN);
    float var = stats[64 + j] * (1.0f / NN) - mean * mean;
    float sc = rsqrtf(var + EPS) * g[j];
    ss[j] = sc;
    ss[64 + j] = beta[j] - mean * sc;
}

// graph offsets from sorted batch
__global__ void k_gptr(const int* __restrict__ batch, int* __restrict__ gptr) {
    int i = blockIdx.x * 256 + threadIdx.x;
    if (i >= NN) return;
    int b = batch[i];
    int prev = (i == 0) ? -1 : batch[i - 1];
    for (int g = prev + 1; g <= b; ++g) gptr[g] = i;
    if (i == NN - 1) {
        for (int g = b + 1; g <= NG; ++g) gptr[g] = NN;
    }
}

// pool(gather) + norm/relu + dot: half-wave per graph
__global__ void k_gfinal(const unsigned* __restrict__ Hb, const int* __restrict__ gptr,
                         const float* __restrict__ ss, const float* __restrict__ lw,
                         const float* __restrict__ lb, float* __restrict__ out) {
    int g = blockIdx.x * 8 + (threadIdx.x >> 5);
    int lt = threadIdx.x & 31;
    if (g >= NG) return;
    int rs = gptr[g], re = gptr[g + 1];
    float m0 = NINF, m1 = NINF, p0 = NINF, p1 = NINF;
    int n = rs;
    for (; n + 4 <= re; n += 4) {
        unsigned v0 = Hb[(size_t)(n + 0) * 32 + lt];
        unsigned v1 = Hb[(size_t)(n + 1) * 32 + lt];
        unsigned v2 = Hb[(size_t)(n + 2) * 32 + lt];
        unsigned v3 = Hb[(size_t)(n + 3) * 32 + lt];
        m0 = fmaxf(m0, fmaxf(blo(v0), blo(v1))); m1 = fmaxf(m1, fmaxf(bhi(v0), bhi(v1)));
        p0 = fmaxf(p0, fmaxf(blo(v2), blo(v3))); p1 = fmaxf(p1, fmaxf(bhi(v2), bhi(v3)));
    }
    for (; n < re; ++n) {
        unsigned v = Hb[(size_t)n * 32 + lt];
        m0 = fmaxf(m0, blo(v)); m1 = fmaxf(m1, bhi(v));
    }
    m0 = fmaxf(m0, p0);
    m1 = fmaxf(m1, p1);
    float a0 = (m0 == NINF) ? 0.f : fmaxf(fmaf(m0, ss[2 * lt], ss[D + 2 * lt]), 0.f);
    float a1 = (m1 == NINF) ? 0.f : fmaxf(fmaf(m1, ss[2 * lt + 1], ss[D + 2 * lt + 1]), 0.f);
    float p = fmaf(a0, lw[2 * lt], a1 * lw[2 * lt + 1]);
    #pragma unroll
    for (int off = 1; off < 32; off <<= 1) p += __shfl_xor(p, off);
    if (lt == 0) out[g] = p + lb[0];
}

extern "C" void kernel_launch(void* const* d_in, const int* in_sizes, int n_in,
                              void* d_out, int out_size, void* d_ws, size_t ws_size,
                              hipStream_t stream) {
    const float* x     = (const float*)d_in[0];
    const int*   ei    = (const int*)d_in[1];
    const float* ea    = (const float*)d_in[2];
    const int*   batch = (const int*)d_in[3];
    const float* Wp[3] = {(const float*)d_in[4],  (const float*)d_in[8],  (const float*)d_in[12]};
    const float* bp[3] = {(const float*)d_in[5],  (const float*)d_in[9],  (const float*)d_in[13]};
    const float* gp[3] = {(const float*)d_in[6],  (const float*)d_in[10], (const float*)d_in[14]};
    const float* tp[3] = {(const float*)d_in[7],  (const float*)d_in[11], (const float*)d_in[15]};
    const float* lw    = (const float*)d_in[16];
    const float* lb    = (const float*)d_in[17];
    float* out = (float*)d_out;

    const int* src = ei;
    const int* dst = ei + NE;

    // workspace layout (u32 words; fill targets 16B-aligned)
    unsigned* w = (unsigned*)d_ws;
    int*      rowptr = (int*)w;                    // 100004
    int*      counts = (int*)(w + 100004);         // 100004
    int*      esrc   = (int*)(w + 200008);         // 1600000
    unsigned* eaggk  = w + 1800008;                // 600000
    int*      bsum   = (int*)(w + 2400008);        // 256
    float*    stats  = (float*)(w + 2400264);      // 128
    float*    ss     = (float*)(w + 2400392);      // 128
    int*      gptr   = (int*)(w + 2400520);        // 1032
    int*      scnt   = (int*)(w + 2401552);        // 256
    // big region (48 MB total): Xb0/Hb1/Hb2 for layers; aliased by CSR scratch pre-cast
    unsigned* Xb0    = w + 2401808;                // 3200000
    unsigned* Hb1    = w + 5601808;                // 3200000
    unsigned* Hb2    = w + 8801808;                // 3200000 (end 12001808 = 48.0 MB)
    int*      cntA   = (int*)Xb0;                  // 196000 (alias; dead after binB)
    unsigned* gbuck  = w + 2601808;                // 196*1000*24 = 4704000 (alias)
    unsigned* sbuf   = w + 7305808;                // 196*1024 = 200704 (alias)

    const int NB = (NN + SCAN_BS - 1) / SCAN_BS;   // 196

    // --- zero fills ---
    k_fill_u32x4<<<(25001 + 255) / 256, 256, 0, stream>>>((uint4*)counts, 0u, 25001);
    k_fill_u32x4<<<1, 64, 0, stream>>>((uint4*)scnt, 0u, 64);
    k_fill_u32x4<<<(150000 + 255) / 256, 256, 0, stream>>>((uint4*)eaggk, ENC_NEGINF, 150000);

    // --- edge_attr seg-max + dst histogram (fused) ---
    k_scatter_e<<<NE / 32, 256, 0, stream>>>(ea, dst, eaggk, counts);

    // --- CSR build: deterministic-slot binning (no global atomics) ---
    k_binA<<<NBLKA, 256, 0, stream>>>(src, dst, gbuck, cntA, scnt, sbuf);
    k_scan1<<<NB, SCAN_BS, 0, stream>>>(counts, rowptr, bsum);
    k_scan2<<<1, 256, 0, stream>>>(bsum, NB);
    k_scan3<<<(NN + 1 + 255) / 256, 256, 0, stream>>>(rowptr, bsum);
    k_binB<<<NBUK, 512, 0, stream>>>(gbuck, cntA, scnt, sbuf, rowptr, esrc);

    // --- bf16 cast (AFTER binB: Xb0 aliases CSR scratch) + graph offsets ---
    k_cast<<<(NN * 16 + 255) / 256, 256, 0, stream>>>((const float4*)x, (uint2*)Xb0, NN * 16);
    k_gptr<<<(NN + 255) / 256, 256, 0, stream>>>(batch, gptr);

    // --- 3 layers: agg (raw bf16 maxima) -> gemm (decode + fused prev norm/relu) ---
    const unsigned* ain[3] = {Xb0, Hb1, Hb2};
    unsigned* abuf[3] = {Hb2, Xb0, Hb1};
    unsigned* hbuf[3] = {Hb1, Hb2, Xb0};
    for (int l = 0; l < 3; ++l) {
        k_agg<<<NN / 8, 256, 0, stream>>>(ain[l], rowptr, esrc, abuf[l]);
        k_fill_u32x4<<<1, 32, 0, stream>>>((uint4*)stats, 0u, 32);
        k_gemm<<<(NN + 63) / 64, 256, 0, stream>>>(abuf[l], eaggk, ss, l > 0 ? 1 : 0,
                                                   Wp[l], bp[l], hbuf[l], stats);
        k_finalize_stats<<<1, 64, 0, stream>>>(stats, gp[l], tp[l], ss);
    }

    // --- pooled gather + final norm/relu/dot ---
    k_gfinal<<<NG / 8, 256, 0, stream>>>(Xb0, gptr, ss, lw, lb, out);
}

// Round 7
// 487.940 us; speedup vs baseline: 3.0863x; 1.1200x over previous
//
#include <hip/hip_runtime.h>

#define NN 100000
#define NE 1600000
#define NG 1024
#define D 64
#define DE 6
#define FAN 70
#define EPS 1e-5f

#define ENC_NEGINF 0x007FFFFFu
#define NINF (-__builtin_inff())

#define NBUK 196      // dst buckets of 512 nodes
#define TILE 1600     // edges per binA block
#define NBLKA 1000    // NE / TILE
#define ACAP 24       // per-(bucket,block) deterministic slot capacity (lambda=8.16)
#define SCAP 1024     // per-bucket spill capacity (rare path)
#define BCAP 10240    // binB LDS esrc capacity

__device__ __forceinline__ unsigned enc(float f) {
    unsigned u = __float_as_uint(f);
    return (u & 0x80000000u) ? ~u : (u | 0x80000000u);
}
__device__ __forceinline__ float dec(unsigned u) {
    return (u & 0x80000000u) ? __uint_as_float(u & 0x7FFFFFFFu) : __uint_as_float(~u);
}
__device__ __forceinline__ unsigned bfr(float f) {   // fp32 -> bf16 bits, RNE
    unsigned u = __float_as_uint(f);
    return (u + 0x7FFFu + ((u >> 16) & 1)) >> 16;
}
__device__ __forceinline__ float blo(unsigned w) { return __uint_as_float(w << 16); }
__device__ __forceinline__ float bhi(unsigned w) { return __uint_as_float(w & 0xFFFF0000u); }

__global__ void k_fill_u32x4(uint4* __restrict__ p, unsigned v, int n4) {
    int i = blockIdx.x * 256 + threadIdx.x;
    if (i < n4) p[i] = make_uint4(v, v, v, v);
}

// fp32 [NN][64] -> bf16-packed [NN][32] u32
__global__ void k_cast(const float4* __restrict__ in, uint2* __restrict__ out, int n4) {
    int i = blockIdx.x * 256 + threadIdx.x;
    if (i < n4) {
        float4 v = in[i];
        out[i] = make_uint2(bfr(v.x) | (bfr(v.y) << 16), bfr(v.z) | (bfr(v.w) << 16));
    }
}

// pass A: deterministic slots gbuck[b][blk][ACAP], entries (eid<<9 | dst&511)
__launch_bounds__(256)
__global__ void k_binA(const int* __restrict__ dst,
                       unsigned* __restrict__ gbuck, int* __restrict__ cntA,
                       int* __restrict__ scnt, unsigned* __restrict__ sbuf) {
    __shared__ int cnt[NBUK];
    int tid = threadIdx.x, blk = blockIdx.x;
    for (int i = tid; i < NBUK; i += 256) cnt[i] = 0;
    __syncthreads();
    int e0 = blk * TILE;
    int e1 = min(e0 + TILE, NE);
    for (int e = e0 + tid; e < e1; e += 256) {
        int d = dst[e];
        int b = d >> 9;
        unsigned ent = ((unsigned)e << 9) | (unsigned)(d & 511);
        int pos = atomicAdd(&cnt[b], 1);
        if (pos < ACAP) gbuck[((size_t)b * NBLKA + blk) * ACAP + pos] = ent;
        else {  // rare spill
            int sp = atomicAdd(&scnt[b], 1);
            if (sp < SCAP) sbuf[b * SCAP + sp] = ent;
        }
    }
    __syncthreads();
    for (int i = tid; i < NBUK; i += 256) cntA[blk * NBUK + i] = min(cnt[i], ACAP);
}

// per-bucket totals
__global__ void k_buksum(const int* __restrict__ cntA, const int* __restrict__ scnt,
                         int* __restrict__ buktot) {
    __shared__ int red[256];
    int b = blockIdx.x, tid = threadIdx.x;
    int sum = 0;
    for (int blk = tid; blk < NBLKA; blk += 256) sum += cntA[blk * NBUK + b];
    red[tid] = sum;
    __syncthreads();
    for (int off = 128; off > 0; off >>= 1) {
        if (tid < off) red[tid] += red[tid + off];
        __syncthreads();
    }
    if (tid == 0) buktot[b] = red[0] + min(scnt[b], SCAP);
}

// exclusive scan of 196 bucket totals
__global__ void k_bukscan(const int* __restrict__ buktot, int* __restrict__ bukbase) {
    __shared__ int s[256];
    int t = threadIdx.x;
    int c = (t < NBUK) ? buktot[t] : 0;
    s[t] = c;
    __syncthreads();
    for (int off = 1; off < 256; off <<= 1) {
        int y = (t >= off) ? s[t - off] : 0;
        __syncthreads();
        s[t] += y;
        __syncthreads();
    }
    if (t < NBUK) bukbase[t] = s[t] - c;
}

// pass B: per bucket — count+scan -> rowptr; scatter esrc via LDS; eagg via LDS atomicMax
__launch_bounds__(512)
__global__ void k_binB(const unsigned* __restrict__ gbuck, const int* __restrict__ cntA,
                       const int* __restrict__ scnt, const unsigned* __restrict__ sbuf,
                       const int* __restrict__ bukbase,
                       const int* __restrict__ src, const float* __restrict__ ea,
                       int* __restrict__ rowptr, int* __restrict__ esrc,
                       unsigned* __restrict__ eaggk) {
    __shared__ int cnt[512];
    __shared__ int base[512];
    __shared__ unsigned el[BCAP];            // 40 KB
    __shared__ unsigned emax[512 * DE];      // 12 KB
    int b = blockIdx.x, tid = threadIdx.x;
    int nb = b << 9;
    int nend = min(nb + 512, NN);
    cnt[tid] = 0;
    for (int i = tid; i < 512 * DE; i += 512) emax[i] = ENC_NEGINF;
    __syncthreads();
    int sc = min(scnt[b], SCAP);
    // pass 1: per-node counts
    for (int blk = tid; blk < NBLKA; blk += 512) {
        int c = cntA[blk * NBUK + b];
        const unsigned* p = &gbuck[((size_t)b * NBLKA + blk) * ACAP];
        for (int i = 0; i < c; ++i) atomicAdd(&cnt[p[i] & 511], 1);
    }
    for (int i = tid; i < sc; i += 512) atomicAdd(&cnt[sbuf[b * SCAP + i] & 511], 1);
    __syncthreads();
    // inclusive scan of 512 counts
    int v = cnt[tid];
    base[tid] = v;
    __syncthreads();
    for (int off = 1; off < 512; off <<= 1) {
        int y = (tid >= off) ? base[tid - off] : 0;
        __syncthreads();
        base[tid] += y;
        __syncthreads();
    }
    int excl = base[tid] - v;
    int rb = bukbase[b];
    if (nb + tid < NN) rowptr[nb + tid] = rb + excl;
    if (b == NBUK - 1 && tid == 0) rowptr[NN] = NE;
    int regsz = base[511];
    __syncthreads();
    cnt[tid] = excl;   // reuse as cursor
    __syncthreads();
    // pass 2: scatter + edge_attr seg-max (LDS)
    if (regsz <= BCAP) {
        for (int blk = tid; blk < NBLKA; blk += 512) {
            int c = cntA[blk * NBUK + b];
            const unsigned* p = &gbuck[((size_t)b * NBLKA + blk) * ACAP];
            for (int i = 0; i < c; ++i) {
                unsigned ent = p[i];
                int loc = ent & 511;
                int eid = ent >> 9;
                int pos = atomicAdd(&cnt[loc], 1);
                el[pos] = (unsigned)src[eid];
                const float* pe = &ea[(size_t)eid * DE];
                #pragma unroll
                for (int t = 0; t < DE; ++t) atomicMax(&emax[loc * DE + t], enc(pe[t]));
            }
        }
        for (int i = tid; i < sc; i += 512) {
            unsigned ent = sbuf[b * SCAP + i];
            int loc = ent & 511;
            int eid = ent >> 9;
            int pos = atomicAdd(&cnt[loc], 1);
            el[pos] = (unsigned)src[eid];
            const float* pe = &ea[(size_t)eid * DE];
            #pragma unroll
            for (int t = 0; t < DE; ++t) atomicMax(&emax[loc * DE + t], enc(pe[t]));
        }
        __syncthreads();
        for (int i = tid; i < regsz; i += 512) esrc[rb + i] = (int)el[i];
    } else {  // capacity fallback: direct global scatter (correct, slower)
        for (int blk = tid; blk < NBLKA; blk += 512) {
            int c = cntA[blk * NBUK + b];
            const unsigned* p = &gbuck[((size_t)b * NBLKA + blk) * ACAP];
            for (int i = 0; i < c; ++i) {
                unsigned ent = p[i];
                int loc = ent & 511;
                int eid = ent >> 9;
                int pos = atomicAdd(&cnt[loc], 1);
                esrc[rb + pos] = src[eid];
                const float* pe = &ea[(size_t)eid * DE];
                #pragma unroll
                for (int t = 0; t < DE; ++t) atomicMax(&emax[loc * DE + t], enc(pe[t]));
            }
        }
        for (int i = tid; i < sc; i += 512) {
            unsigned ent = sbuf[b * SCAP + i];
            int loc = ent & 511;
            int eid = ent >> 9;
            int pos = atomicAdd(&cnt[loc], 1);
            esrc[rb + pos] = src[eid];
            const float* pe = &ea[(size_t)eid * DE];
            #pragma unroll
            for (int t = 0; t < DE; ++t) atomicMax(&emax[loc * DE + t], enc(pe[t]));
        }
        __syncthreads();
    }
    // coalesced eagg out (encoded; k_gemm decodes, ENC_NEGINF -> 0)
    for (int i = tid; i < (nend - nb) * DE; i += 512) eaggk[nb * DE + i] = emax[i];
}

// ---------------- gather-max: half-wave per node, raw bf16 maxima out ----------------
__global__ void k_agg(const unsigned* __restrict__ Xb, const int* __restrict__ rowptr,
                      const int* __restrict__ esrc, unsigned* __restrict__ Ab) {
    int n = blockIdx.x * 8 + (threadIdx.x >> 5);
    int lt = threadIdx.x & 31;
    if (n >= NN) return;
    int rs = rowptr[n], re = rowptr[n + 1];
    float m0 = NINF, m1 = NINF, p0 = NINF, p1 = NINF;
    int j = rs;
    for (; j + 16 <= re; j += 16) {
        unsigned v0 = Xb[(size_t)esrc[j + 0] * 32 + lt],  v1 = Xb[(size_t)esrc[j + 1] * 32 + lt];
        unsigned v2 = Xb[(size_t)esrc[j + 2] * 32 + lt],  v3 = Xb[(size_t)esrc[j + 3] * 32 + lt];
        unsigned v4 = Xb[(size_t)esrc[j + 4] * 32 + lt],  v5 = Xb[(size_t)esrc[j + 5] * 32 + lt];
        unsigned v6 = Xb[(size_t)esrc[j + 6] * 32 + lt],  v7 = Xb[(size_t)esrc[j + 7] * 32 + lt];
        unsigned v8 = Xb[(size_t)esrc[j + 8] * 32 + lt],  v9 = Xb[(size_t)esrc[j + 9] * 32 + lt];
        unsigned va = Xb[(size_t)esrc[j + 10] * 32 + lt], vb = Xb[(size_t)esrc[j + 11] * 32 + lt];
        unsigned vc = Xb[(size_t)esrc[j + 12] * 32 + lt], vd = Xb[(size_t)esrc[j + 13] * 32 + lt];
        unsigned ve = Xb[(size_t)esrc[j + 14] * 32 + lt], vf = Xb[(size_t)esrc[j + 15] * 32 + lt];
        m0 = fmaxf(m0, fmaxf(fmaxf(blo(v0), blo(v1)), fmaxf(blo(v2), blo(v3))));
        p0 = fmaxf(p0, fmaxf(fmaxf(blo(v4), blo(v5)), fmaxf(blo(v6), blo(v7))));
        m0 = fmaxf(m0, fmaxf(fmaxf(blo(v8), blo(v9)), fmaxf(blo(va), blo(vb))));
        p0 = fmaxf(p0, fmaxf(fmaxf(blo(vc), blo(vd)), fmaxf(blo(ve), blo(vf))));
        m1 = fmaxf(m1, fmaxf(fmaxf(bhi(v0), bhi(v1)), fmaxf(bhi(v2), bhi(v3))));
        p1 = fmaxf(p1, fmaxf(fmaxf(bhi(v4), bhi(v5)), fmaxf(bhi(v6), bhi(v7))));
        m1 = fmaxf(m1, fmaxf(fmaxf(bhi(v8), bhi(v9)), fmaxf(bhi(va), bhi(vb))));
        p1 = fmaxf(p1, fmaxf(fmaxf(bhi(vc), bhi(vd)), fmaxf(bhi(ve), bhi(vf))));
    }
    for (; j + 4 <= re; j += 4) {
        unsigned v0 = Xb[(size_t)esrc[j + 0] * 32 + lt], v1 = Xb[(size_t)esrc[j + 1] * 32 + lt];
        unsigned v2 = Xb[(size_t)esrc[j + 2] * 32 + lt], v3 = Xb[(size_t)esrc[j + 3] * 32 + lt];
        m0 = fmaxf(m0, fmaxf(blo(v0), blo(v1))); p0 = fmaxf(p0, fmaxf(blo(v2), blo(v3)));
        m1 = fmaxf(m1, fmaxf(bhi(v0), bhi(v1))); p1 = fmaxf(p1, fmaxf(bhi(v2), bhi(v3)));
    }
    for (; j < re; ++j) {
        unsigned v = Xb[(size_t)esrc[j] * 32 + lt];
        m0 = fmaxf(m0, blo(v)); m1 = fmaxf(m1, bhi(v));
    }
    m0 = fmaxf(m0, p0);
    m1 = fmaxf(m1, p1);
    Ab[(size_t)n * 32 + lt] = bfr(m0) | (bfr(m1) << 16);
}

// ---------------- GEMM: decode A (+prev-layer norm/relu), compute h, stats ----------------
__launch_bounds__(256)
__global__ void k_gemm(const unsigned* __restrict__ Ab, const unsigned* __restrict__ eaggk,
                       const float* __restrict__ ss, int apply,
                       const float* __restrict__ W, const float* __restrict__ b,
                       unsigned* __restrict__ Hb, float* __restrict__ stats) {
    __shared__ float Wl[FAN][D];    // 17.9 KB
    __shared__ float Ag[64][74];    // 18.9 KB
    __shared__ float ls[128];

    int tid = threadIdx.x;
    int n0 = blockIdx.x * 64;

    for (int i = tid; i < FAN * D; i += 256) Wl[i >> 6][i & 63] = W[i];
    for (int i = tid; i < 64 * 32; i += 256) {
        int r = i >> 5, c2 = i & 31;
        int n = n0 + r;
        unsigned wv = (n < NN) ? Ab[(size_t)n * 32 + c2] : 0xFF80FF80u;
        float a0 = blo(wv), a1 = bhi(wv);
        if (apply) {
            a0 = (a0 == NINF) ? 0.f : fmaxf(fmaf(a0, ss[2 * c2], ss[D + 2 * c2]), 0.f);
            a1 = (a1 == NINF) ? 0.f : fmaxf(fmaf(a1, ss[2 * c2 + 1], ss[D + 2 * c2 + 1]), 0.f);
        } else {
            a0 = (a0 == NINF) ? 0.f : a0;
            a1 = (a1 == NINF) ? 0.f : a1;
        }
        *(float2*)&Ag[r][2 * c2] = make_float2(a0, a1);
    }
    for (int i = tid; i < 64 * 8; i += 256) {
        int r = i >> 3, c = i & 7;
        int n = n0 + r;
        float v = 0.f;
        if (c < DE && n < NN) {
            unsigned u = eaggk[n * DE + c];
            v = (u == ENC_NEGINF) ? 0.f : dec(u);
        }
        Ag[r][64 + c] = v;
    }
    if (tid < 128) ls[tid] = 0.f;
    __syncthreads();

    int tr = tid >> 4, tc = tid & 15;
    int r0 = tr * 4, c0 = tc * 4;
    float acc[4][4];
    #pragma unroll
    for (int i = 0; i < 4; i++)
        #pragma unroll
        for (int jj = 0; jj < 4; jj++) acc[i][jj] = 0.f;

    for (int k = 0; k < FAN; k++) {
        float4 wv = *(const float4*)&Wl[k][c0];
        float a0 = Ag[r0 + 0][k];
        float a1 = Ag[r0 + 1][k];
        float a2 = Ag[r0 + 2][k];
        float a3 = Ag[r0 + 3][k];
        acc[0][0] = fmaf(a0, wv.x, acc[0][0]); acc[0][1] = fmaf(a0, wv.y, acc[0][1]);
        acc[0][2] = fmaf(a0, wv.z, acc[0][2]); acc[0][3] = fmaf(a0, wv.w, acc[0][3]);
        acc[1][0] = fmaf(a1, wv.x, acc[1][0]); acc[1][1] = fmaf(a1, wv.y, acc[1][1]);
        acc[1][2] = fmaf(a1, wv.z, acc[1][2]); acc[1][3] = fmaf(a1, wv.w, acc[1][3]);
        acc[2][0] = fmaf(a2, wv.x, acc[2][0]); acc[2][1] = fmaf(a2, wv.y, acc[2][1]);
        acc[2][2] = fmaf(a2, wv.z, acc[2][2]); acc[2][3] = fmaf(a2, wv.w, acc[2][3]);
        acc[3][0] = fmaf(a3, wv.x, acc[3][0]); acc[3][1] = fmaf(a3, wv.y, acc[3][1]);
        acc[3][2] = fmaf(a3, wv.z, acc[3][2]); acc[3][3] = fmaf(a3, wv.w, acc[3][3]);
    }

    float4 bb = *(const float4*)&b[c0];
    float cs[4] = {0.f, 0.f, 0.f, 0.f};
    float cq[4] = {0.f, 0.f, 0.f, 0.f};
    #pragma unroll
    for (int i = 0; i < 4; i++) {
        int n = n0 + r0 + i;
        if (n < NN) {
            float ox = acc[i][0] + bb.x, oy = acc[i][1] + bb.y;
            float oz = acc[i][2] + bb.z, ow = acc[i][3] + bb.w;
            uint2 pk = make_uint2(bfr(ox) | (bfr(oy) << 16), bfr(oz) | (bfr(ow) << 16));
            *(uint2*)&Hb[(size_t)n * 32 + (c0 >> 1)] = pk;
            cs[0] += ox; cs[1] += oy; cs[2] += oz; cs[3] += ow;
            cq[0] += ox * ox; cq[1] += oy * oy; cq[2] += oz * oz; cq[3] += ow * ow;
        }
    }
    #pragma unroll
    for (int jj = 0; jj < 4; jj++) {
        atomicAdd(&ls[c0 + jj], cs[jj]);
        atomicAdd(&ls[64 + c0 + jj], cq[jj]);
    }
    __syncthreads();
    if (tid < 128) atomicAdd(&stats[tid], ls[tid]);
}

__global__ void k_finalize_stats(const float* __restrict__ stats, const float* __restrict__ g,
                                 const float* __restrict__ beta, float* __restrict__ ss) {
    int j = threadIdx.x;  // 64 threads
    float mean = stats[j] * (1.0f / NN);
    float var = stats[64 + j] * (1.0f / NN) - mean * mean;
    float sc = rsqrtf(var + EPS) * g[j];
    ss[j] = sc;
    ss[64 + j] = beta[j] - mean * sc;
}

// graph offsets from sorted batch
__global__ void k_gptr(const int* __restrict__ batch, int* __restrict__ gptr) {
    int i = blockIdx.x * 256 + threadIdx.x;
    if (i >= NN) return;
    int b = batch[i];
    int prev = (i == 0) ? -1 : batch[i - 1];
    for (int g = prev + 1; g <= b; ++g) gptr[g] = i;
    if (i == NN - 1) {
        for (int g = b + 1; g <= NG; ++g) gptr[g] = NN;
    }
}

// pool(gather) + norm/relu + dot: half-wave per graph
__global__ void k_gfinal(const unsigned* __restrict__ Hb, const int* __restrict__ gptr,
                         const float* __restrict__ ss, const float* __restrict__ lw,
                         const float* __restrict__ lb, float* __restrict__ out) {
    int g = blockIdx.x * 8 + (threadIdx.x >> 5);
    int lt = threadIdx.x & 31;
    if (g >= NG) return;
    int rs = gptr[g], re = gptr[g + 1];
    float m0 = NINF, m1 = NINF, p0 = NINF, p1 = NINF;
    int n = rs;
    for (; n + 4 <= re; n += 4) {
        unsigned v0 = Hb[(size_t)(n + 0) * 32 + lt];
        unsigned v1 = Hb[(size_t)(n + 1) * 32 + lt];
        unsigned v2 = Hb[(size_t)(n + 2) * 32 + lt];
        unsigned v3 = Hb[(size_t)(n + 3) * 32 + lt];
        m0 = fmaxf(m0, fmaxf(blo(v0), blo(v1))); m1 = fmaxf(m1, fmaxf(bhi(v0), bhi(v1)));
        p0 = fmaxf(p0, fmaxf(blo(v2), blo(v3))); p1 = fmaxf(p1, fmaxf(bhi(v2), bhi(v3)));
    }
    for (; n < re; ++n) {
        unsigned v = Hb[(size_t)n * 32 + lt];
        m0 = fmaxf(m0, blo(v)); m1 = fmaxf(m1, bhi(v));
    }
    m0 = fmaxf(m0, p0);
    m1 = fmaxf(m1, p1);
    float a0 = (m0 == NINF) ? 0.f : fmaxf(fmaf(m0, ss[2 * lt], ss[D + 2 * lt]), 0.f);
    float a1 = (m1 == NINF) ? 0.f : fmaxf(fmaf(m1, ss[2 * lt + 1], ss[D + 2 * lt + 1]), 0.f);
    float p = fmaf(a0, lw[2 * lt], a1 * lw[2 * lt + 1]);
    #pragma unroll
    for (int off = 1; off < 32; off <<= 1) p += __shfl_xor(p, off);
    if (lt == 0) out[g] = p + lb[0];
}

extern "C" void kernel_launch(void* const* d_in, const int* in_sizes, int n_in,
                              void* d_out, int out_size, void* d_ws, size_t ws_size,
                              hipStream_t stream) {
    const float* x     = (const float*)d_in[0];
    const int*   ei    = (const int*)d_in[1];
    const float* ea    = (const float*)d_in[2];
    const int*   batch = (const int*)d_in[3];
    const float* Wp[3] = {(const float*)d_in[4],  (const float*)d_in[8],  (const float*)d_in[12]};
    const float* bp[3] = {(const float*)d_in[5],  (const float*)d_in[9],  (const float*)d_in[13]};
    const float* gp[3] = {(const float*)d_in[6],  (const float*)d_in[10], (const float*)d_in[14]};
    const float* tp[3] = {(const float*)d_in[7],  (const float*)d_in[11], (const float*)d_in[15]};
    const float* lw    = (const float*)d_in[16];
    const float* lb    = (const float*)d_in[17];
    float* out = (float*)d_out;

    const int* src = ei;
    const int* dst = ei + NE;

    // workspace layout (u32 words; fill targets 16B-aligned)
    unsigned* w = (unsigned*)d_ws;
    int*      rowptr  = (int*)w;                   // 100004
    int*      esrc    = (int*)(w + 100004);        // 1600000
    unsigned* eaggk   = w + 1700004;               // 600000
    float*    stats   = (float*)(w + 2300004);     // 128
    float*    ss      = (float*)(w + 2300132);     // 128
    int*      gptr    = (int*)(w + 2300260);       // 1032
    int*      scnt    = (int*)(w + 2301292);       // 256
    int*      buktot  = (int*)(w + 2301548);       // 256
    int*      bukbase = (int*)(w + 2301804);       // 256
    // big region: Xb0/Hb1/Hb2 for layers; CSR scratch aliases it (dead before k_cast)
    unsigned* Xb0     = w + 2302064;               // 3200000
    unsigned* Hb1     = w + 5502064;               // 3200000
    unsigned* Hb2     = w + 8702064;               // 3200000 (end 11902064 = 47.6 MB)
    int*      cntA    = (int*)Xb0;                 // 196000 (alias)
    unsigned* gbuck   = w + 2502064;               // 4704000 (alias)
    unsigned* sbuf    = w + 7206064;               // 200704 (alias)

    // --- zero spill counters ---
    k_fill_u32x4<<<1, 64, 0, stream>>>((uint4*)scnt, 0u, 64);

    // --- CSR build + edge_attr seg-max, all via deterministic-slot binning ---
    k_binA<<<NBLKA, 256, 0, stream>>>(dst, gbuck, cntA, scnt, sbuf);
    k_buksum<<<NBUK, 256, 0, stream>>>(cntA, scnt, buktot);
    k_bukscan<<<1, 256, 0, stream>>>(buktot, bukbase);
    k_binB<<<NBUK, 512, 0, stream>>>(gbuck, cntA, scnt, sbuf, bukbase, src, ea,
                                     rowptr, esrc, eaggk);

    // --- bf16 cast (AFTER binB: Xb0 aliases CSR scratch) + graph offsets ---
    k_cast<<<(NN * 16 + 255) / 256, 256, 0, stream>>>((const float4*)x, (uint2*)Xb0, NN * 16);
    k_gptr<<<(NN + 255) / 256, 256, 0, stream>>>(batch, gptr);

    // --- 3 layers: agg (raw bf16 maxima) -> gemm (decode + fused prev norm/relu) ---
    const unsigned* ain[3] = {Xb0, Hb1, Hb2};
    unsigned* abuf[3] = {Hb2, Xb0, Hb1};
    unsigned* hbuf[3] = {Hb1, Hb2, Xb0};
    for (int l = 0; l < 3; ++l) {
        k_agg<<<NN / 8, 256, 0, stream>>>(ain[l], rowptr, esrc, abuf[l]);
        k_fill_u32x4<<<1, 32, 0, stream>>>((uint4*)stats, 0u, 32);
        k_gemm<<<(NN + 63) / 64, 256, 0, stream>>>(abuf[l], eaggk, ss, l > 0 ? 1 : 0,
                                                   Wp[l], bp[l], hbuf[l], stats);
        k_finalize_stats<<<1, 64, 0, stream>>>(stats, gp[l], tp[l], ss);
    }

    // --- pooled gather + final norm/relu/dot ---
    k_gfinal<<<NG / 8, 256, 0, stream>>>(Xb0, gptr, ss, lw, lb, out);
}